// Round 17
// baseline (845.578 us; speedup 1.0000x reference)
//
#include <hip/hip_runtime.h>

#define S 25
#define PLANE 625
#define VOL 390625
#define CLn 12500000  // ushorts per channels-last activation buffer
#define HREG2 7168    // ushorts per ci-half region (896 wave-aligned 16B chunks)
#define DBUF 14336    // ushorts per LDS buffer (2 ci-half regions); 2 buffers = 57344 B

typedef __attribute__((ext_vector_type(8))) short short8;
typedef __attribute__((ext_vector_type(4))) float f32x4;
typedef __attribute__((ext_vector_type(16))) float f32x16;
typedef __attribute__((ext_vector_type(4))) unsigned short us4;
typedef __attribute__((ext_vector_type(4))) unsigned int u32x4;

__device__ __forceinline__ unsigned short f2bf(float f) {
    unsigned int u = __float_as_uint(f);
    u += 0x7fffu + ((u >> 16) & 1u);
    return (unsigned short)(u >> 16);
}

// async global->LDS, 16B per lane: dest = lds base (wave-uniform) + lane*16
__device__ __forceinline__ void glds16(const unsigned short* g, unsigned short* l) {
    __builtin_amdgcn_global_load_lds(
        (const __attribute__((address_space(1))) unsigned int*)g,
        (__attribute__((address_space(3))) unsigned int*)l, 16, 0, 0);
}

// bijective XCD-chunk swizzle (m204)
__device__ __forceinline__ int xcd_swz(int orig, int nwg) {
    int q = nwg >> 3, r = nwg & 7;
    int x = orig & 7, lid = orig >> 3;
    return (x < r ? x * (q + 1) : r * (q + 1) + (x - r) * q) + lid;
}

__device__ __forceinline__ int nxt_kd(int kd, int d0, int d1) {
    #pragma unroll 1
    for (++kd; kd < 25; ++kd) {
        int kd0 = kd / 5, kd1 = kd - kd0 * 5;
        int e0 = d0 + kd0 - 2, e1 = d1 + kd1 - 2;
        if (e0 >= 0 && e0 < S && e1 >= 0 && e1 < S) return kd;
    }
    return 25;
}

// next valid slab, uv in [.., uhi*8), V=8 window columns
__device__ __forceinline__ int nxt_wr(int uv, int uhi, int b0, int b1) {
    #pragma unroll 1
    for (++uv; uv < uhi * 8; ++uv) {
        int u = uv >> 3, v = uv & 7;
        int e0 = b0 + u, e1 = b1 + v;
        if (e0 >= 0 && e0 < S && e1 >= 0 && e1 < S) return uv;
    }
    return uhi * 8;
}

// ---------------- weight prep (r15, unchanged) -----------------------------
__global__ __launch_bounds__(256) void prep_weights(
    const float* __restrict__ w2a, const float* __restrict__ w2b,
    const float* __restrict__ w0, const float* __restrict__ w1,
    unsigned short* __restrict__ wbig32, unsigned short* __restrict__ wl1,
    unsigned short* __restrict__ wcp, unsigned short* __restrict__ z16)
{
    int idx = blockIdx.x * 256 + threadIdx.x;
    if (idx < 320000) {
        int k = idx & 15;
        int m = (idx >> 4) & 31;
        int rem = idx >> 9;             // kd01*25 + t
        int t = rem % 25, kd01 = rem / 25;
        float v;
        if (m < 16) v = w2a[(m * 16 + k) * 625 + kd01 * 25 + t];
        else        v = w2a[((m - 16) * 16 + k) * 625 + t * 25 + kd01];
        wbig32[idx] = f2bf(v);
    } else if (idx < 345600) {
        int j = idx - 320000;
        int k = j & 31;
        int row = (j >> 5) & 15;
        int tile = (j >> 9) & 1;
        int kd01 = j >> 10;
        int kd0 = kd01 / 5, kd1 = kd01 - kd0 * 5;
        float v = 0.f;
        if (k < 25) {
            int t = k, kd2 = t / 5, kd3 = t - kd2 * 5;
            if (tile == 0) {
                v = (row < 8) ? w1[row * 625 + kd0 * 125 + kd1 * 25 + t]
                              : w1[(row - 8) * 625 + t * 25 + kd01];
            } else {
                if (row < 8) {
                    if (kd0 >= 1 && kd0 <= 3 && kd1 >= 1 && kd1 <= 3)
                        v = w0[((row * 3 + (kd0 - 1)) * 3 + (kd1 - 1)) * 25 + t];
                } else {
                    if (kd2 >= 1 && kd2 <= 3 && kd3 >= 1 && kd3 <= 3)
                        v = w0[(row - 8) * 225 + ((kd2 - 1) * 3 + (kd3 - 1)) * 25 + kd01];
                }
            }
        }
        wl1[j] = f2bf(v);
    } else if (idx < 345600 + 614400) {
        int j = idx - 345600;
        int k = j & 31;
        int row = (j >> 5) & 15;
        int rem = j >> 9;               // uv*25 + t
        int t = rem % 25, uv = rem / 25;
        int u = uv >> 3, v8 = uv & 7;
        int path = row & 1, o = row >> 1;
        int py = o >> 2, px = o & 3;
        int kd0 = u - py, kd1 = v8 - px;
        float v = 0.f;
        if (kd0 >= 0 && kd0 < 5 && kd1 >= 0 && kd1 < 5) {
            int ci = k & 15;
            if (path == 0 && k < 16)
                v = w2b[ci * 625 + (kd0 * 5 + kd1) * 25 + t];
            else if (path == 1 && k >= 16)
                v = w2b[ci * 625 + t * 25 + kd0 * 5 + kd1];
        }
        wcp[j] = f2bf(v);
    } else if (idx < 345600 + 614400 + 8) {
        z16[idx - 960000] = 0;          // 16B zero block for OOB glds lanes
    }
}

// ---------------- layer 1, MFMA over taps (unchanged) ----------------------
__global__ __launch_bounds__(256) void layer1_mfma(
    const float* __restrict__ x, const unsigned short* __restrict__ wl1,
    const float* __restrict__ b0, const float* __restrict__ b1,
    unsigned short* __restrict__ hbf)
{
    __shared__ __align__(16) unsigned short pl[29 * 32];
    const int blk = blockIdx.x;
    const int b = blk / PLANE;
    const int d01 = blk - b * PLANE;
    const int d0 = d01 / S, d1 = d01 - d0 * S;
    const int tid = threadIdx.x;
    const int l = tid & 63, w = tid >> 6;
    const int col = l & 15, kq = l >> 4;

    int off[8];
    #pragma unroll
    for (int j = 0; j < 8; ++j) {
        int t = kq * 8 + j; if (t > 24) t = 24;
        int t5 = t / 5;
        off[j] = t5 * 32 + (t - t5 * 5);
    }
    int rb[10];
    #pragma unroll
    for (int g = 0; g < 10; ++g) {
        int n = (w * 10 + g) * 16 + col; if (n > 624) n = 624;
        int d2 = n / 25;
        rb[g] = d2 * 32 + (n - d2 * 25);
    }

    f32x4 acc0[10], acc1[10];
    #pragma unroll
    for (int g = 0; g < 10; ++g) {
        acc0[g] = (f32x4){0.f, 0.f, 0.f, 0.f};
        acc1[g] = (f32x4){0.f, 0.f, 0.f, 0.f};
    }

    const float* xb = x + (size_t)b * VOL;

    #pragma unroll 1
    for (int kd01 = 0; kd01 < 25; ++kd01) {
        const int kd0 = kd01 / 5, kd1 = kd01 - kd0 * 5;
        const int e0 = d0 + kd0 - 2, e1 = d1 + kd1 - 2;
        if (e0 < 0 || e0 >= S || e1 < 0 || e1 >= S) continue;
        __syncthreads();
        {
            const float* sp = xb + (e0 * 25 + e1) * 625;
            for (int i = tid; i < 841; i += 256) {
                int r = i / 29, c = i - r * 29;
                float v = 0.f;
                if (r >= 2 && r <= 26 && c >= 2 && c <= 26)
                    v = sp[(r - 2) * 25 + (c - 2)];
                pl[r * 32 + c] = f2bf(v);
            }
        }
        __syncthreads();
        const unsigned short* wp = wl1 + kd01 * 1024;
        short8 a0 = *(const short8*)(wp + col * 32 + kq * 8);
        short8 a1 = *(const short8*)(wp + 512 + col * 32 + kq * 8);
        #pragma unroll
        for (int g = 0; g < 10; ++g) {
            short8 bf;
            #pragma unroll
            for (int j = 0; j < 8; ++j)
                bf[j] = (short)pl[rb[g] + off[j]];
            acc0[g] = __builtin_amdgcn_mfma_f32_16x16x32_bf16(a0, bf, acc0[g], 0, 0, 0);
            acc1[g] = __builtin_amdgcn_mfma_f32_16x16x32_bf16(a1, bf, acc1[g], 0, 0, 0);
        }
    }

    const int ch = (kq & 1) * 4;
    float bi1[4], bi0[4];
    #pragma unroll
    for (int r = 0; r < 4; ++r) { bi1[r] = b1[ch + r]; bi0[r] = b0[ch + r]; }
    const bool lo = (kq < 2);
    const size_t obase = (size_t)(b * 625 + d01) * 625;
    #pragma unroll
    for (int g = 0; g < 10; ++g) {
        int n = (w * 10 + g) * 16 + col;
        float r0[4], r1[4];
        #pragma unroll
        for (int r = 0; r < 4; ++r) {
            r0[r] = fmaxf(acc0[g][r] + bi1[r], 0.f);
            r1[r] = fmaxf(acc1[g][r] + bi0[r], 0.f);
        }
        us4 u0, u1;
        #pragma unroll
        for (int r = 0; r < 4; ++r) {
            float p0 = __shfl_xor(r0[r], 32, 64);
            float p1 = __shfl_xor(r1[r], 32, 64);
            u0[r] = f2bf(r0[r] + p0);
            u1[r] = f2bf(r1[r] + p1);
        }
        if (lo && n < 625) {
            *(us4*)&hbf[(obase + n) * 16 + 8 + ch] = u0;
            *(us4*)&hbf[(obase + n) * 16 + ch]     = u1;
        }
    }
}

// ---------------- conv16x16 fused pair: 32x32x16, glds + LDS DOUBLE-BUFFER -
// One barrier per slab: barrier -> issue glds slab k+1 into buf^1 -> compute
// slab k from buf (loads land under the ~1200-cyc MFMA phase; the barrier's
// implicit vmcnt(0) is then free). r15/r16 issued loads at loop bottom,
// immediately drained by the top barrier -> full L2 latency exposed per slab.
__global__ __launch_bounds__(256, 2) void conv_mfma32(
    const unsigned short* __restrict__ in, const unsigned short* __restrict__ wq,
    const float* __restrict__ bias, const unsigned short* __restrict__ z16,
    unsigned short* __restrict__ gA, unsigned short* __restrict__ gB)
{
    __shared__ __align__(16) unsigned short pl[2 * DBUF];  // 57344 B
    const int blk = xcd_swz(blockIdx.x, 1250);
    const int b = blk / PLANE;
    const int d01 = blk - b * PLANE;
    const int d0 = d01 / S, d1 = d01 - d0 * S;
    const int tid = threadIdx.x;
    const int l = tid & 63, w = tid >> 6;
    const int h = l >> 5;        // K-half (8 ci)
    const int nl = l & 31;       // point-in-group / A-row

    int srcofs[7]; bool okz[7];
    #pragma unroll
    for (int j = 0; j < 7; ++j) {
        int cid = (j * 4 + w) * 64 + l;
        int half = (cid >= 896) ? 1 : 0;
        int pt = cid - half * 896;
        int r = pt / 29, c = pt - r * 29;
        okz[j] = (pt < 841) && (r >= 2 && r <= 26 && c >= 2 && c <= 26);
        srcofs[j] = ((r - 2) * 25 + (c - 2)) * 16 + half * 8;
    }

    int rbo[5];
    #pragma unroll
    for (int g = 0; g < 5; ++g) {
        int n = (w * 5 + g) * 32 + nl;
        if (n > 624) n = 624;
        int d2 = n / 25, d3 = n - d2 * 25;
        rbo[g] = h * HREG2 + (d2 * 29 + d3) * 8;
    }

    f32x16 acc[5];
    #pragma unroll
    for (int g = 0; g < 5; ++g)
        #pragma unroll
        for (int r = 0; r < 16; ++r) acc[g][r] = 0.f;

    const unsigned short* inb = in + (size_t)b * 6250000;

    int kd_cur = nxt_kd(-1, d0, d1);
    {   // prologue: slab0 -> buf0
        int kd0 = kd_cur / 5, kd1 = kd_cur - kd0 * 5;
        const unsigned short* sb = inb + (size_t)((d0 + kd0 - 2) * 25 + (d1 + kd1 - 2)) * 10000;
        #pragma unroll
        for (int j = 0; j < 7; ++j)
            glds16(okz[j] ? sb + srcofs[j] : z16, &pl[(j * 4 + w) * 512]);
    }
    int kd_nxt = nxt_kd(kd_cur, d0, d1);
    int cur = 0;

    #pragma unroll 1
    while (kd_cur < 25) {
        __syncthreads();   // drains vmcnt: buf[cur] ready; all waves done with buf[cur^1]

        if (kd_nxt < 25) {  // issue slab k+1 into the other buffer (overlaps compute)
            int kd0 = kd_nxt / 5, kd1 = kd_nxt - kd0 * 5;
            const unsigned short* sb = inb + (size_t)((d0 + kd0 - 2) * 25 + (d1 + kd1 - 2)) * 10000;
            unsigned short* dst = &pl[(cur ^ 1) * DBUF];
            #pragma unroll
            for (int j = 0; j < 7; ++j)
                glds16(okz[j] ? sb + srcofs[j] : z16, dst + (j * 4 + w) * 512);
        }

        const unsigned short* bp = &pl[cur * DBUF];
        const unsigned short* wkd = wq + (size_t)kd_cur * 12800 + nl * 16 + h * 8;
        #pragma unroll 1
        for (int t = 0; t < 25; ++t) {
            short8 a = *(const short8*)(wkd + t * 512);
            int t5 = t / 5;
            int toff = (t5 * 29 + (t - t5 * 5)) * 8;
            #pragma unroll
            for (int g = 0; g < 5; ++g) {
                short8 bf = *(const short8*)&bp[rbo[g] + toff];
                acc[g] = __builtin_amdgcn_mfma_f32_32x32x16_bf16(a, bf, acc[g], 0, 0, 0);
            }
        }

        cur ^= 1;
        kd_cur = kd_nxt;
        kd_nxt = nxt_kd(kd_cur, d0, d1);
    }

    // epilogue: reg q*4+r -> row = r + 8q + 4h; row<16 -> gA co=row, else gB
    #pragma unroll
    for (int g = 0; g < 5; ++g) {
        int n = (w * 5 + g) * 32 + nl;
        if (n < 625) {
            size_t ob = ((size_t)(b * 625 + d01) * 625 + n) * 16;
            #pragma unroll
            for (int q = 0; q < 4; ++q) {
                int baserow = q * 8 + 4 * h;
                us4 u;
                #pragma unroll
                for (int r = 0; r < 4; ++r) {
                    int co = (baserow + r) & 15;
                    u[r] = f2bf(fmaxf(acc[g][q * 4 + r] + bias[co], 0.f));
                }
                if (baserow < 16) *(us4*)&gA[ob + baserow] = u;
                else              *(us4*)&gB[ob + baserow - 16] = u;
            }
        }
    }
}

// ---------------- convc: 2x4-patch 16->1 pair, HALF-WINDOW split (r16) -----
__global__ __launch_bounds__(128, 2) void convc_v3(
    const unsigned short* __restrict__ gA,   // gB = gA + CLn
    const unsigned short* __restrict__ wcp,
    float* __restrict__ part)
{
    __shared__ __align__(16) unsigned short pl[348 * 36];
    const int blk = xcd_swz(blockIdx.x, 1456);
    const int hw = blk & 1;                 // half-window id
    const int rest = blk >> 1;
    const int q = rest & 3;
    const int geo = rest >> 2;
    const int b = geo / 91;
    const int g91 = geo - b * 91;
    const int t0 = g91 / 7, t1 = g91 - t0 * 7;
    const int D0 = t0 * 2, D1 = t1 * 4;
    const int ulo = 3 * hw, uhi = 3 * hw + 3;
    const int r0 = (q == 0) ? -2 : (q == 1) ? 4 : (q == 2) ? 10 : 17;
    const int tid = threadIdx.x;
    const int l = tid & 63, w = tid >> 6;
    const int col = l & 15, kq = l >> 4;

    int ofsG[11], ofsL[11]; bool ok[11];
    #pragma unroll
    for (int j = 0; j < 11; ++j) {
        int cid = tid + j * 128;
        int p = cid >> 2, qq = cid & 3;  // qq<2: gA halves, qq>=2: gB halves
        int r = p / 29, c = p - r * 29;
        int d2e = r + r0, d3e = c - 2;
        ok[j] = (cid < 1392) && (d2e >= 0 && d2e < S) && (d3e >= 0 && d3e < S);
        ofsG[j] = (qq >> 1) * CLn + (d2e * 25 + d3e) * 16 + (qq & 1) * 8;
        ofsL[j] = p * 36 + qq * 8;
    }

    int rb[5];
    #pragma unroll
    for (int g = 0; g < 5; ++g) {
        int n = q * 160 + (w * 5 + g) * 16 + col; if (n > 624) n = 624;
        int d2 = n / 25;
        rb[g] = ((d2 - r0 - 2) * 29 + (n - d2 * 25)) * 36;
    }

    f32x4 acc[5];
    #pragma unroll
    for (int g = 0; g < 5; ++g) acc[g] = (f32x4){0.f, 0.f, 0.f, 0.f};

    const unsigned short* gAb = gA + (size_t)b * 6250000;

    u32x4 stg[11];
    int uv_cur = nxt_wr(ulo * 8 - 1, uhi, D0 - 2, D1 - 2);
    if (uv_cur < uhi * 8) {
        int u = uv_cur >> 3, v = uv_cur & 7;
        const unsigned short* sb = gAb + (size_t)((D0 - 2 + u) * 25 + (D1 - 2 + v)) * 10000;
        #pragma unroll
        for (int j = 0; j < 11; ++j) {
            u32x4 z = {0u, 0u, 0u, 0u};
            if (ok[j]) z = *(const u32x4*)(sb + ofsG[j]);
            stg[j] = z;
        }
    }

    #pragma unroll 1
    while (uv_cur < uhi * 8) {
        const int uvc = uv_cur;
        const int uv_nxt = nxt_wr(uv_cur, uhi, D0 - 2, D1 - 2);
        __syncthreads();
        #pragma unroll
        for (int j = 0; j < 11; ++j)
            if (j < 10 || tid < 112) *(u32x4*)&pl[ofsL[j]] = stg[j];
        __syncthreads();
        if (uv_nxt < uhi * 8) {
            int u = uv_nxt >> 3, v = uv_nxt & 7;
            const unsigned short* sb = gAb + (size_t)((D0 - 2 + u) * 25 + (D1 - 2 + v)) * 10000;
            #pragma unroll
            for (int j = 0; j < 11; ++j) {
                u32x4 z = {0u, 0u, 0u, 0u};
                if (ok[j]) z = *(const u32x4*)(sb + ofsG[j]);
                stg[j] = z;
            }
        }

        const unsigned short* wbase = wcp + (size_t)uvc * 12800;  // 25*16*32
        #pragma unroll 1
        for (int t = 0; t < 25; ++t) {
            const int t5 = t / 5;
            const int toff = (t5 * 29 + (t - t5 * 5)) * 36;
            short8 a = *(const short8*)(wbase + (t * 16 + col) * 32 + kq * 8);
            #pragma unroll
            for (int g = 0; g < 5; ++g) {
                short8 bf = *(const short8*)&pl[rb[g] + toff + kq * 8];
                acc[g] = __builtin_amdgcn_mfma_f32_16x16x32_bf16(a, bf, acc[g], 0, 0, 0);
            }
        }
        uv_cur = uv_nxt;
    }

    // C row = kq*4+reg; row = o*2+path; o = py*4+px. Store raw partials.
    #pragma unroll
    for (int g = 0; g < 5; ++g) {
        int n = q * 160 + (w * 5 + g) * 16 + col;
        if (n < 625) {
            #pragma unroll
            for (int r2 = 0; r2 < 2; ++r2) {
                int o = kq * 2 + r2;
                int d0 = D0 + (o >> 2), d1 = D1 + (o & 3);
                if (d0 < S && d1 < S) {
                    size_t pidx = (size_t)(d0 * 25 + d1) * 625 + n;
                    part[((size_t)((hw * 2 + 0) * 2 + b)) * VOL + pidx] = acc[g][r2 * 2];
                    part[((size_t)((hw * 2 + 1) * 2 + b)) * VOL + pidx] = acc[g][r2 * 2 + 1];
                }
            }
        }
    }
}

// ---------------- convc_fin: combine partials, bias+relu, store ------------
__global__ __launch_bounds__(256) void convc_fin(
    const float* __restrict__ part, const float* __restrict__ b2b,
    float* __restrict__ outp)
{
    int idx = blockIdx.x * 256 + threadIdx.x;
    if (idx >= 2 * VOL) return;
    int b = idx / VOL;
    int p = idx - b * VOL;
    const float bv = b2b[0];
    float A = part[(size_t)(0 * 2 + b) * VOL + p] + part[(size_t)(4 + b) * VOL + p];
    float B = part[(size_t)(2 + b) * VOL + p] + part[(size_t)(6 + b) * VOL + p];
    outp[idx] = fmaxf(A + bv, 0.f) + fmaxf(B + bv, 0.f);
}

extern "C" void kernel_launch(void* const* d_in, const int* in_sizes, int n_in,
                              void* d_out, int out_size, void* d_ws, size_t ws_size,
                              hipStream_t stream) {
    const float* x   = (const float*)d_in[0];
    const float* w0  = (const float*)d_in[1];
    const float* b0  = (const float*)d_in[2];
    const float* w1  = (const float*)d_in[3];
    const float* b1  = (const float*)d_in[4];
    const float* w2a = (const float*)d_in[5];
    const float* b2a = (const float*)d_in[6];
    const float* w2b = (const float*)d_in[7];
    const float* b2b = (const float*)d_in[8];
    float* out = (float*)d_out;

    // ws layout (ushort units): hbf | gA | gB | wbig32 | wl1 | wcp | z16 | part(f32)
    unsigned short* hbf    = (unsigned short*)d_ws;
    unsigned short* gA     = hbf + CLn;
    unsigned short* gB     = gA + CLn;               // must stay gA+CLn
    unsigned short* wbig32 = gB + CLn;               // 320000
    unsigned short* wl1    = wbig32 + 320000;        // 25600
    unsigned short* wcp    = wl1 + 25600;            // 614400
    unsigned short* z16    = wcp + 614400;           // 8 (16B zero block)
    float* part = (float*)(z16 + 8);                 // 8 * VOL f32 = 12.5 MB
    if (ws_size < ((size_t)3 * CLn + 320000 + 25600 + 614400 + 8) * sizeof(unsigned short)
                  + (size_t)8 * VOL * sizeof(float)) return;

    prep_weights<<<3751, 256, 0, stream>>>(w2a, w2b, w0, w1, wbig32, wl1, wcp, z16);
    layer1_mfma<<<1250, 256, 0, stream>>>(x, wl1, b0, b1, hbf);
    conv_mfma32<<<1250, 256, 0, stream>>>(hbf, wbig32, b2a, z16, gA, gB);
    convc_v3<<<1456, 128, 0, stream>>>(gA, wcp, part);
    convc_fin<<<3052, 256, 0, stream>>>(part, b2b, out);
}

// Round 18
// 817.323 us; speedup vs baseline: 1.0346x; 1.0346x over previous
//
#include <hip/hip_runtime.h>

#define S 25
#define PLANE 625
#define VOL 390625
#define CLn 12500000  // ushorts per channels-last activation buffer
#define HREG2 7168    // ushorts per ci-half region (896 wave-aligned 16B chunks)
#define LDSPAD 20224  // pad conv_mfma LDS to 40448 B -> L2-friendly residency regime (r10/r11)

typedef __attribute__((ext_vector_type(8))) short short8;
typedef __attribute__((ext_vector_type(4))) float f32x4;
typedef __attribute__((ext_vector_type(16))) float f32x16;
typedef __attribute__((ext_vector_type(4))) unsigned short us4;
typedef __attribute__((ext_vector_type(4))) unsigned int u32x4;

__device__ __forceinline__ unsigned short f2bf(float f) {
    unsigned int u = __float_as_uint(f);
    u += 0x7fffu + ((u >> 16) & 1u);
    return (unsigned short)(u >> 16);
}

// async global->LDS, 16B per lane: dest = lds base (wave-uniform) + lane*16
__device__ __forceinline__ void glds16(const unsigned short* g, unsigned short* l) {
    __builtin_amdgcn_global_load_lds(
        (const __attribute__((address_space(1))) unsigned int*)g,
        (__attribute__((address_space(3))) unsigned int*)l, 16, 0, 0);
}

// bijective XCD-chunk swizzle (m204)
__device__ __forceinline__ int xcd_swz(int orig, int nwg) {
    int q = nwg >> 3, r = nwg & 7;
    int x = orig & 7, lid = orig >> 3;
    return (x < r ? x * (q + 1) : r * (q + 1) + (x - r) * q) + lid;
}

__device__ __forceinline__ int nxt_kd(int kd, int d0, int d1) {
    #pragma unroll 1
    for (++kd; kd < 25; ++kd) {
        int kd0 = kd / 5, kd1 = kd - kd0 * 5;
        int e0 = d0 + kd0 - 2, e1 = d1 + kd1 - 2;
        if (e0 >= 0 && e0 < S && e1 >= 0 && e1 < S) return kd;
    }
    return 25;
}

// next valid slab, uv in [.., uhi*8), V=8 window columns
__device__ __forceinline__ int nxt_wr(int uv, int uhi, int b0, int b1) {
    #pragma unroll 1
    for (++uv; uv < uhi * 8; ++uv) {
        int u = uv >> 3, v = uv & 7;
        int e0 = b0 + u, e1 = b1 + v;
        if (e0 >= 0 && e0 < S && e1 >= 0 && e1 < S) return uv;
    }
    return uhi * 8;
}

// ---------------- weight prep -----------------------------------------------
__global__ __launch_bounds__(256) void prep_weights(
    const float* __restrict__ w2a, const float* __restrict__ w2b,
    const float* __restrict__ w0, const float* __restrict__ w1,
    unsigned short* __restrict__ wbig32, unsigned short* __restrict__ wl1,
    unsigned short* __restrict__ wcp, unsigned short* __restrict__ z16)
{
    int idx = blockIdx.x * 256 + threadIdx.x;
    if (idx < 320000) {
        int k = idx & 15;
        int m = (idx >> 4) & 31;
        int rem = idx >> 9;             // kd01*25 + t
        int t = rem % 25, kd01 = rem / 25;
        float v;
        if (m < 16) v = w2a[(m * 16 + k) * 625 + kd01 * 25 + t];
        else        v = w2a[((m - 16) * 16 + k) * 625 + t * 25 + kd01];
        wbig32[idx] = f2bf(v);
    } else if (idx < 345600) {
        int j = idx - 320000;
        int k = j & 31;
        int row = (j >> 5) & 15;
        int tile = (j >> 9) & 1;
        int kd01 = j >> 10;
        int kd0 = kd01 / 5, kd1 = kd01 - kd0 * 5;
        float v = 0.f;
        if (k < 25) {
            int t = k, kd2 = t / 5, kd3 = t - kd2 * 5;
            if (tile == 0) {
                v = (row < 8) ? w1[row * 625 + kd0 * 125 + kd1 * 25 + t]
                              : w1[(row - 8) * 625 + t * 25 + kd01];
            } else {
                if (row < 8) {
                    if (kd0 >= 1 && kd0 <= 3 && kd1 >= 1 && kd1 <= 3)
                        v = w0[((row * 3 + (kd0 - 1)) * 3 + (kd1 - 1)) * 25 + t];
                } else {
                    if (kd2 >= 1 && kd2 <= 3 && kd3 >= 1 && kd3 <= 3)
                        v = w0[(row - 8) * 225 + ((kd2 - 1) * 3 + (kd3 - 1)) * 25 + kd01];
                }
            }
        }
        wl1[j] = f2bf(v);
    } else if (idx < 345600 + 614400) {
        int j = idx - 345600;
        int k = j & 31;
        int row = (j >> 5) & 15;
        int rem = j >> 9;               // uv*25 + t
        int t = rem % 25, uv = rem / 25;
        int u = uv >> 3, v8 = uv & 7;
        int path = row & 1, o = row >> 1;
        int py = o >> 2, px = o & 3;
        int kd0 = u - py, kd1 = v8 - px;
        float v = 0.f;
        if (kd0 >= 0 && kd0 < 5 && kd1 >= 0 && kd1 < 5) {
            int ci = k & 15;
            if (path == 0 && k < 16)
                v = w2b[ci * 625 + (kd0 * 5 + kd1) * 25 + t];
            else if (path == 1 && k >= 16)
                v = w2b[ci * 625 + t * 25 + kd0 * 5 + kd1];
        }
        wcp[j] = f2bf(v);
    } else if (idx < 345600 + 614400 + 8) {
        z16[idx - 960000] = 0;          // 16B zero block for OOB glds lanes
    }
}

// ---------------- layer 1, MFMA over taps ----------------------------------
__global__ __launch_bounds__(256) void layer1_mfma(
    const float* __restrict__ x, const unsigned short* __restrict__ wl1,
    const float* __restrict__ b0, const float* __restrict__ b1,
    unsigned short* __restrict__ hbf)
{
    __shared__ __align__(16) unsigned short pl[29 * 32];
    const int blk = blockIdx.x;
    const int b = blk / PLANE;
    const int d01 = blk - b * PLANE;
    const int d0 = d01 / S, d1 = d01 - d0 * S;
    const int tid = threadIdx.x;
    const int l = tid & 63, w = tid >> 6;
    const int col = l & 15, kq = l >> 4;

    int off[8];
    #pragma unroll
    for (int j = 0; j < 8; ++j) {
        int t = kq * 8 + j; if (t > 24) t = 24;
        int t5 = t / 5;
        off[j] = t5 * 32 + (t - t5 * 5);
    }
    int rb[10];
    #pragma unroll
    for (int g = 0; g < 10; ++g) {
        int n = (w * 10 + g) * 16 + col; if (n > 624) n = 624;
        int d2 = n / 25;
        rb[g] = d2 * 32 + (n - d2 * 25);
    }

    f32x4 acc0[10], acc1[10];
    #pragma unroll
    for (int g = 0; g < 10; ++g) {
        acc0[g] = (f32x4){0.f, 0.f, 0.f, 0.f};
        acc1[g] = (f32x4){0.f, 0.f, 0.f, 0.f};
    }

    const float* xb = x + (size_t)b * VOL;

    #pragma unroll 1
    for (int kd01 = 0; kd01 < 25; ++kd01) {
        const int kd0 = kd01 / 5, kd1 = kd01 - kd0 * 5;
        const int e0 = d0 + kd0 - 2, e1 = d1 + kd1 - 2;
        if (e0 < 0 || e0 >= S || e1 < 0 || e1 >= S) continue;
        __syncthreads();
        {
            const float* sp = xb + (e0 * 25 + e1) * 625;
            for (int i = tid; i < 841; i += 256) {
                int r = i / 29, c = i - r * 29;
                float v = 0.f;
                if (r >= 2 && r <= 26 && c >= 2 && c <= 26)
                    v = sp[(r - 2) * 25 + (c - 2)];
                pl[r * 32 + c] = f2bf(v);
            }
        }
        __syncthreads();
        const unsigned short* wp = wl1 + kd01 * 1024;
        short8 a0 = *(const short8*)(wp + col * 32 + kq * 8);
        short8 a1 = *(const short8*)(wp + 512 + col * 32 + kq * 8);
        #pragma unroll
        for (int g = 0; g < 10; ++g) {
            short8 bf;
            #pragma unroll
            for (int j = 0; j < 8; ++j)
                bf[j] = (short)pl[rb[g] + off[j]];
            acc0[g] = __builtin_amdgcn_mfma_f32_16x16x32_bf16(a0, bf, acc0[g], 0, 0, 0);
            acc1[g] = __builtin_amdgcn_mfma_f32_16x16x32_bf16(a1, bf, acc1[g], 0, 0, 0);
        }
    }

    const int ch = (kq & 1) * 4;
    float bi1[4], bi0[4];
    #pragma unroll
    for (int r = 0; r < 4; ++r) { bi1[r] = b1[ch + r]; bi0[r] = b0[ch + r]; }
    const bool lo = (kq < 2);
    const size_t obase = (size_t)(b * 625 + d01) * 625;
    #pragma unroll
    for (int g = 0; g < 10; ++g) {
        int n = (w * 10 + g) * 16 + col;
        float r0[4], r1[4];
        #pragma unroll
        for (int r = 0; r < 4; ++r) {
            r0[r] = fmaxf(acc0[g][r] + bi1[r], 0.f);
            r1[r] = fmaxf(acc1[g][r] + bi0[r], 0.f);
        }
        us4 u0, u1;
        #pragma unroll
        for (int r = 0; r < 4; ++r) {
            float p0 = __shfl_xor(r0[r], 32, 64);
            float p1 = __shfl_xor(r1[r], 32, 64);
            u0[r] = f2bf(r0[r] + p0);
            u1[r] = f2bf(r1[r] + p1);
        }
        if (lo && n < 625) {
            *(us4*)&hbf[(obase + n) * 16 + 8 + ch] = u0;
            *(us4*)&hbf[(obase + n) * 16 + ch]     = u1;
        }
    }
}

// ---------------- conv16x16 fused pair: 32x32x16, glds staging (r15/r16) ---
__global__ __launch_bounds__(256, 3) void conv_mfma32(
    const unsigned short* __restrict__ in, const unsigned short* __restrict__ wq,
    const float* __restrict__ bias, const unsigned short* __restrict__ z16,
    unsigned short* __restrict__ gA, unsigned short* __restrict__ gB)
{
    __shared__ __align__(16) unsigned short pl[LDSPAD];  // uses [0, 2*HREG2)
    const int blk = xcd_swz(blockIdx.x, 1250);
    const int b = blk / PLANE;
    const int d01 = blk - b * PLANE;
    const int d0 = d01 / S, d1 = d01 - d0 * S;
    const int tid = threadIdx.x;
    const int l = tid & 63, w = tid >> 6;
    const int h = l >> 5;        // K-half (8 ci)
    const int nl = l & 31;       // point-in-group / A-row

    int srcofs[7]; bool okz[7];
    #pragma unroll
    for (int j = 0; j < 7; ++j) {
        int cid = (j * 4 + w) * 64 + l;
        int half = (cid >= 896) ? 1 : 0;
        int pt = cid - half * 896;
        int r = pt / 29, c = pt - r * 29;
        okz[j] = (pt < 841) && (r >= 2 && r <= 26 && c >= 2 && c <= 26);
        srcofs[j] = ((r - 2) * 25 + (c - 2)) * 16 + half * 8;
    }

    int rbo[5];
    #pragma unroll
    for (int g = 0; g < 5; ++g) {
        int n = (w * 5 + g) * 32 + nl;
        if (n > 624) n = 624;
        int d2 = n / 25, d3 = n - d2 * 25;
        rbo[g] = h * HREG2 + (d2 * 29 + d3) * 8;
    }

    f32x16 acc[5];
    #pragma unroll
    for (int g = 0; g < 5; ++g)
        #pragma unroll
        for (int r = 0; r < 16; ++r) acc[g][r] = 0.f;

    const unsigned short* inb = in + (size_t)b * 6250000;

    int kd_cur = nxt_kd(-1, d0, d1);
    {
        int kd0 = kd_cur / 5, kd1 = kd_cur - kd0 * 5;
        const unsigned short* sb = inb + (size_t)((d0 + kd0 - 2) * 25 + (d1 + kd1 - 2)) * 10000;
        #pragma unroll
        for (int j = 0; j < 7; ++j)
            glds16(okz[j] ? sb + srcofs[j] : z16, &pl[(j * 4 + w) * 512]);
    }

    #pragma unroll 1
    while (kd_cur < 25) {
        const int kd01 = kd_cur;
        const int kd_nxt = nxt_kd(kd_cur, d0, d1);
        __syncthreads();   // drains vmcnt: slab loads have landed

        const unsigned short* wkd = wq + (size_t)kd01 * 12800 + nl * 16 + h * 8;
        #pragma unroll 1
        for (int t = 0; t < 25; ++t) {
            short8 a = *(const short8*)(wkd + t * 512);
            int t5 = t / 5;
            int toff = (t5 * 29 + (t - t5 * 5)) * 8;
            #pragma unroll
            for (int g = 0; g < 5; ++g) {
                short8 bf = *(const short8*)&pl[rbo[g] + toff];
                acc[g] = __builtin_amdgcn_mfma_f32_32x32x16_bf16(a, bf, acc[g], 0, 0, 0);
            }
        }

        __syncthreads();   // all waves done reading LDS
        if (kd_nxt < 25) {
            int kd0 = kd_nxt / 5, kd1 = kd_nxt - kd0 * 5;
            const unsigned short* sb = inb + (size_t)((d0 + kd0 - 2) * 25 + (d1 + kd1 - 2)) * 10000;
            #pragma unroll
            for (int j = 0; j < 7; ++j)
                glds16(okz[j] ? sb + srcofs[j] : z16, &pl[(j * 4 + w) * 512]);
        }
        kd_cur = kd_nxt;
    }

    #pragma unroll
    for (int g = 0; g < 5; ++g) {
        int n = (w * 5 + g) * 32 + nl;
        if (n < 625) {
            size_t ob = ((size_t)(b * 625 + d01) * 625 + n) * 16;
            #pragma unroll
            for (int q = 0; q < 4; ++q) {
                int baserow = q * 8 + 4 * h;
                us4 u;
                #pragma unroll
                for (int r = 0; r < 4; ++r) {
                    int co = (baserow + r) & 15;
                    u[r] = f2bf(fmaxf(acc[g][q * 4 + r] + bias[co], 0.f));
                }
                if (baserow < 16) *(us4*)&gA[ob + baserow] = u;
                else              *(us4*)&gB[ob + baserow - 16] = u;
            }
        }
    }
}

// ---------------- convc: 2x4-patch 16->1 pair, HALF-WINDOW split (r16) -----
__global__ __launch_bounds__(128, 2) void convc_v3(
    const unsigned short* __restrict__ gA,   // gB = gA + CLn
    const unsigned short* __restrict__ wcp,
    float* __restrict__ part)
{
    __shared__ __align__(16) unsigned short pl[348 * 36];
    const int blk = xcd_swz(blockIdx.x, 1456);
    const int hw = blk & 1;                 // half-window id
    const int rest = blk >> 1;
    const int q = rest & 3;
    const int geo = rest >> 2;
    const int b = geo / 91;
    const int g91 = geo - b * 91;
    const int t0 = g91 / 7, t1 = g91 - t0 * 7;
    const int D0 = t0 * 2, D1 = t1 * 4;
    const int ulo = 3 * hw, uhi = 3 * hw + 3;
    const int r0 = (q == 0) ? -2 : (q == 1) ? 4 : (q == 2) ? 10 : 17;
    const int tid = threadIdx.x;
    const int l = tid & 63, w = tid >> 6;
    const int col = l & 15, kq = l >> 4;

    int ofsG[11], ofsL[11]; bool ok[11];
    #pragma unroll
    for (int j = 0; j < 11; ++j) {
        int cid = tid + j * 128;
        int p = cid >> 2, qq = cid & 3;  // qq<2: gA halves, qq>=2: gB halves
        int r = p / 29, c = p - r * 29;
        int d2e = r + r0, d3e = c - 2;
        ok[j] = (cid < 1392) && (d2e >= 0 && d2e < S) && (d3e >= 0 && d3e < S);
        ofsG[j] = (qq >> 1) * CLn + (d2e * 25 + d3e) * 16 + (qq & 1) * 8;
        ofsL[j] = p * 36 + qq * 8;
    }

    int rb[5];
    #pragma unroll
    for (int g = 0; g < 5; ++g) {
        int n = q * 160 + (w * 5 + g) * 16 + col; if (n > 624) n = 624;
        int d2 = n / 25;
        rb[g] = ((d2 - r0 - 2) * 29 + (n - d2 * 25)) * 36;
    }

    f32x4 acc[5];
    #pragma unroll
    for (int g = 0; g < 5; ++g) acc[g] = (f32x4){0.f, 0.f, 0.f, 0.f};

    const unsigned short* gAb = gA + (size_t)b * 6250000;

    u32x4 stg[11];
    int uv_cur = nxt_wr(ulo * 8 - 1, uhi, D0 - 2, D1 - 2);
    if (uv_cur < uhi * 8) {
        int u = uv_cur >> 3, v = uv_cur & 7;
        const unsigned short* sb = gAb + (size_t)((D0 - 2 + u) * 25 + (D1 - 2 + v)) * 10000;
        #pragma unroll
        for (int j = 0; j < 11; ++j) {
            u32x4 z = {0u, 0u, 0u, 0u};
            if (ok[j]) z = *(const u32x4*)(sb + ofsG[j]);
            stg[j] = z;
        }
    }

    #pragma unroll 1
    while (uv_cur < uhi * 8) {
        const int uvc = uv_cur;
        const int uv_nxt = nxt_wr(uv_cur, uhi, D0 - 2, D1 - 2);
        __syncthreads();
        #pragma unroll
        for (int j = 0; j < 11; ++j)
            if (j < 10 || tid < 112) *(u32x4*)&pl[ofsL[j]] = stg[j];
        __syncthreads();
        if (uv_nxt < uhi * 8) {
            int u = uv_nxt >> 3, v = uv_nxt & 7;
            const unsigned short* sb = gAb + (size_t)((D0 - 2 + u) * 25 + (D1 - 2 + v)) * 10000;
            #pragma unroll
            for (int j = 0; j < 11; ++j) {
                u32x4 z = {0u, 0u, 0u, 0u};
                if (ok[j]) z = *(const u32x4*)(sb + ofsG[j]);
                stg[j] = z;
            }
        }

        const unsigned short* wbase = wcp + (size_t)uvc * 12800;  // 25*16*32
        #pragma unroll 1
        for (int t = 0; t < 25; ++t) {
            const int t5 = t / 5;
            const int toff = (t5 * 29 + (t - t5 * 5)) * 36;
            short8 a = *(const short8*)(wbase + (t * 16 + col) * 32 + kq * 8);
            #pragma unroll
            for (int g = 0; g < 5; ++g) {
                short8 bf = *(const short8*)&pl[rb[g] + toff + kq * 8];
                acc[g] = __builtin_amdgcn_mfma_f32_16x16x32_bf16(a, bf, acc[g], 0, 0, 0);
            }
        }
        uv_cur = uv_nxt;
    }

    // C row = kq*4+reg; row = o*2+path; o = py*4+px. Store raw partials.
    #pragma unroll
    for (int g = 0; g < 5; ++g) {
        int n = q * 160 + (w * 5 + g) * 16 + col;
        if (n < 625) {
            #pragma unroll
            for (int r2 = 0; r2 < 2; ++r2) {
                int o = kq * 2 + r2;
                int d0 = D0 + (o >> 2), d1 = D1 + (o & 3);
                if (d0 < S && d1 < S) {
                    size_t pidx = (size_t)(d0 * 25 + d1) * 625 + n;
                    part[((size_t)((hw * 2 + 0) * 2 + b)) * VOL + pidx] = acc[g][r2 * 2];
                    part[((size_t)((hw * 2 + 1) * 2 + b)) * VOL + pidx] = acc[g][r2 * 2 + 1];
                }
            }
        }
    }
}

// ---------------- convc_fin: combine partials, bias+relu, store ------------
__global__ __launch_bounds__(256) void convc_fin(
    const float* __restrict__ part, const float* __restrict__ b2b,
    float* __restrict__ outp)
{
    int idx = blockIdx.x * 256 + threadIdx.x;
    if (idx >= 2 * VOL) return;
    int b = idx / VOL;
    int p = idx - b * VOL;
    const float bv = b2b[0];
    float A = part[(size_t)(0 * 2 + b) * VOL + p] + part[(size_t)(4 + b) * VOL + p];
    float B = part[(size_t)(2 + b) * VOL + p] + part[(size_t)(6 + b) * VOL + p];
    outp[idx] = fmaxf(A + bv, 0.f) + fmaxf(B + bv, 0.f);
}

extern "C" void kernel_launch(void* const* d_in, const int* in_sizes, int n_in,
                              void* d_out, int out_size, void* d_ws, size_t ws_size,
                              hipStream_t stream) {
    const float* x   = (const float*)d_in[0];
    const float* w0  = (const float*)d_in[1];
    const float* b0  = (const float*)d_in[2];
    const float* w1  = (const float*)d_in[3];
    const float* b1  = (const float*)d_in[4];
    const float* w2a = (const float*)d_in[5];
    const float* b2a = (const float*)d_in[6];
    const float* w2b = (const float*)d_in[7];
    const float* b2b = (const float*)d_in[8];
    float* out = (float*)d_out;

    // ws layout (ushort units): hbf | gA | gB | wbig32 | wl1 | wcp | z16 | part(f32)
    unsigned short* hbf    = (unsigned short*)d_ws;
    unsigned short* gA     = hbf + CLn;
    unsigned short* gB     = gA + CLn;               // must stay gA+CLn
    unsigned short* wbig32 = gB + CLn;               // 320000
    unsigned short* wl1    = wbig32 + 320000;        // 25600
    unsigned short* wcp    = wl1 + 25600;            // 614400
    unsigned short* z16    = wcp + 614400;           // 8 (16B zero block)
    float* part = (float*)(z16 + 8);                 // 8 * VOL f32 = 12.5 MB
    if (ws_size < ((size_t)3 * CLn + 320000 + 25600 + 614400 + 8) * sizeof(unsigned short)
                  + (size_t)8 * VOL * sizeof(float)) return;

    prep_weights<<<3751, 256, 0, stream>>>(w2a, w2b, w0, w1, wbig32, wl1, wcp, z16);
    layer1_mfma<<<1250, 256, 0, stream>>>(x, wl1, b0, b1, hbf);
    conv_mfma32<<<1250, 256, 0, stream>>>(hbf, wbig32, b2a, z16, gA, gB);
    convc_v3<<<1456, 128, 0, stream>>>(gA, wcp, part);
    convc_fin<<<3052, 256, 0, stream>>>(part, b2b, out);
}